// Round 1
// baseline (1608.938 us; speedup 1.0000x reference)
//
#include <hip/hip_runtime.h>

#define N_NODES 50000
#define IN_CH   256
#define Z_DIM   64
#define N_EDGES 800000
#define CH2     128                       // combined mu|logstd channels
#define NODE_OFF (N_NODES * Z_DIM)        // offset of logstd block in d_out

// ---------------- degree ----------------
__global__ void k_init_deg(float* __restrict__ deg) {
    int i = blockIdx.x * 256 + threadIdx.x;
    if (i < N_NODES) deg[i] = 1.0f;       // self-loop
}

__global__ void k_edge_deg(const int* __restrict__ dst, float* __restrict__ deg) {
    int e = blockIdx.x * 256 + threadIdx.x;
    if (e < N_EDGES) unsafeAtomicAdd(&deg[dst[e]], 1.0f);
}

__global__ void k_dinv(const float* __restrict__ deg, float* __restrict__ dinv) {
    int i = blockIdx.x * 256 + threadIdx.x;
    if (i < N_NODES) dinv[i] = rsqrtf(deg[i]);
}

// ---------------- fused GEMM: xw[N,128] = x @ [W_mu | W_logstd] ----------------
// BM=64, BN=128(full), BK=32, 256 threads, 8x4 micro-tile per thread.
__global__ __launch_bounds__(256) void k_gemm(const float* __restrict__ x,
                                              const float* __restrict__ Wmu,
                                              const float* __restrict__ Wls,
                                              float* __restrict__ xw) {
    __shared__ float As[64][32];
    __shared__ float Bs[32][CH2];
    const int tid = threadIdx.x;
    const int i0  = blockIdx.x * 64;
    const int tx  = tid & 31;   // col group: cols tx*4 .. tx*4+3
    const int ty  = tid >> 5;   // row group: rows ty*8 .. ty*8+7

    float acc[8][4];
#pragma unroll
    for (int r = 0; r < 8; ++r)
#pragma unroll
        for (int j = 0; j < 4; ++j) acc[r][j] = 0.0f;

    for (int k0 = 0; k0 < IN_CH; k0 += 32) {
        // A tile: 64x32 = 512 float4, 2 per thread
#pragma unroll
        for (int l = 0; l < 2; ++l) {
            int f   = tid + l * 256;
            int row = f >> 3;
            int c4  = f & 7;
            float4 v = make_float4(0.f, 0.f, 0.f, 0.f);
            if (i0 + row < N_NODES)
                v = *(const float4*)(x + (size_t)(i0 + row) * IN_CH + k0 + c4 * 4);
            *(float4*)&As[row][c4 * 4] = v;
        }
        // B tile: 32x128 = 1024 float4, 4 per thread (cols <64 from Wmu, >=64 from Wls)
#pragma unroll
        for (int l = 0; l < 4; ++l) {
            int f   = tid + l * 256;
            int row = f >> 5;
            int c   = (f & 31) * 4;
            const float* wp = (c < 64) ? (Wmu + (size_t)(k0 + row) * 64 + c)
                                       : (Wls + (size_t)(k0 + row) * 64 + (c - 64));
            *(float4*)&Bs[row][c] = *(const float4*)wp;
        }
        __syncthreads();

#pragma unroll
        for (int kk = 0; kk < 32; kk += 4) {
            float4 b0 = *(const float4*)&Bs[kk + 0][tx * 4];
            float4 b1 = *(const float4*)&Bs[kk + 1][tx * 4];
            float4 b2 = *(const float4*)&Bs[kk + 2][tx * 4];
            float4 b3 = *(const float4*)&Bs[kk + 3][tx * 4];
#pragma unroll
            for (int r = 0; r < 8; ++r) {
                float4 a = *(const float4*)&As[ty * 8 + r][kk];
                acc[r][0] += a.x * b0.x + a.y * b1.x + a.z * b2.x + a.w * b3.x;
                acc[r][1] += a.x * b0.y + a.y * b1.y + a.z * b2.y + a.w * b3.y;
                acc[r][2] += a.x * b0.z + a.y * b1.z + a.z * b2.z + a.w * b3.z;
                acc[r][3] += a.x * b0.w + a.y * b1.w + a.z * b2.w + a.w * b3.w;
            }
        }
        __syncthreads();
    }

#pragma unroll
    for (int r = 0; r < 8; ++r) {
        int row = i0 + ty * 8 + r;
        if (row < N_NODES) {
            float4 v = make_float4(acc[r][0], acc[r][1], acc[r][2], acc[r][3]);
            *(float4*)(xw + (size_t)row * CH2 + tx * 4) = v;
        }
    }
}

// ---------------- out init: self-loop + bias ----------------
// out[mu  block][i][c] = xw[i][c]    * dinv[i]^2 + b_mu[c]
// out[std block][i][c] = xw[i][c+64] * dinv[i]^2 + b_logstd[c]
__global__ __launch_bounds__(256) void k_init_out(const float* __restrict__ xw,
                                                  const float* __restrict__ dinv,
                                                  const float* __restrict__ bmu,
                                                  const float* __restrict__ bls,
                                                  float* __restrict__ out) {
    int g = blockIdx.x * 256 + threadIdx.x;   // [0, N_NODES*32)
    int i = g >> 5, lane = g & 31;
    if (i >= N_NODES) return;
    float s = dinv[i];
    s = s * s;
    float4 v = ((const float4*)xw)[(size_t)i * 32 + lane];
    int c0 = lane * 4;
    const float* bb = (c0 < 64) ? (bmu + c0) : (bls + (c0 - 64));
    float4 b = *(const float4*)bb;
    float* o = (c0 < 64) ? (out + (size_t)i * 64 + c0)
                         : (out + NODE_OFF + (size_t)i * 64 + (c0 - 64));
    float4 r = make_float4(v.x * s + b.x, v.y * s + b.y, v.z * s + b.z, v.w * s + b.w);
    *(float4*)o = r;
}

// ---------------- edge scatter: out[dst] += xw[src] * dinv[src]*dinv[dst] ----------------
__global__ __launch_bounds__(256) void k_edge(const int* __restrict__ src,
                                              const int* __restrict__ dst,
                                              const float* __restrict__ xw,
                                              const float* __restrict__ dinv,
                                              float* __restrict__ out) {
    int g = blockIdx.x * 256 + threadIdx.x;   // [0, N_EDGES*32)
    int e = g >> 5, lane = g & 31;
    if (e >= N_EDGES) return;
    int s = src[e];
    int d = dst[e];
    float nrm = dinv[s] * dinv[d];
    float4 v = ((const float4*)xw)[(size_t)s * 32 + lane];
    int c0 = lane * 4;
    float* o = (c0 < 64) ? (out + (size_t)d * 64 + c0)
                         : (out + NODE_OFF + (size_t)d * 64 + (c0 - 64));
    unsafeAtomicAdd(o + 0, v.x * nrm);
    unsafeAtomicAdd(o + 1, v.y * nrm);
    unsafeAtomicAdd(o + 2, v.z * nrm);
    unsafeAtomicAdd(o + 3, v.w * nrm);
}

extern "C" void kernel_launch(void* const* d_in, const int* in_sizes, int n_in,
                              void* d_out, int out_size, void* d_ws, size_t ws_size,
                              hipStream_t stream) {
    const float* x   = (const float*)d_in[0];
    const int*   ei  = (const int*)d_in[1];     // [2, E] flat: row0 = src, row1 = dst
    const float* Wmu = (const float*)d_in[2];
    const float* bmu = (const float*)d_in[3];
    const float* Wls = (const float*)d_in[4];
    const float* bls = (const float*)d_in[5];
    float* out = (float*)d_out;

    const int* src = ei;
    const int* dst = ei + N_EDGES;

    char* ws   = (char*)d_ws;
    float* deg  = (float*)ws;                        // 50000 f32
    float* dinv = deg + N_NODES;                     // 50000 f32
    float* xw   = (float*)(ws + 512 * 1024);         // 50000 x 128 f32 = 25.6 MB

    k_init_deg<<<(N_NODES + 255) / 256, 256, 0, stream>>>(deg);
    k_edge_deg<<<(N_EDGES + 255) / 256, 256, 0, stream>>>(dst, deg);
    k_dinv<<<(N_NODES + 255) / 256, 256, 0, stream>>>(deg, dinv);
    k_gemm<<<(N_NODES + 63) / 64, 256, 0, stream>>>(x, Wmu, Wls, xw);
    k_init_out<<<(N_NODES * 32 + 255) / 256, 256, 0, stream>>>(xw, dinv, bmu, bls, out);
    k_edge<<<(N_EDGES * 32 + 255) / 256, 256, 0, stream>>>(src, dst, xw, dinv, out);
}

// Round 2
// 356.140 us; speedup vs baseline: 4.5177x; 4.5177x over previous
//
#include <hip/hip_runtime.h>

#define N_NODES 50000
#define IN_CH   256
#define Z_DIM   64
#define N_EDGES 800000
#define CH2     128
#define NODE_OFF (N_NODES * Z_DIM)
#define NBLK    ((N_NODES + 255) / 256)   // 196

// ---------------- histogram (int) ----------------
__global__ void k_zero_cnt(int* __restrict__ cnt) {
    int i = blockIdx.x * 256 + threadIdx.x;
    if (i < N_NODES) cnt[i] = 0;
}

__global__ void k_hist(const int* __restrict__ dst, int* __restrict__ cnt) {
    int e = blockIdx.x * 256 + threadIdx.x;
    if (e < N_EDGES) atomicAdd(&cnt[dst[e]], 1);
}

__global__ void k_dinv(const int* __restrict__ cnt, float* __restrict__ dinv) {
    int i = blockIdx.x * 256 + threadIdx.x;
    if (i < N_NODES) dinv[i] = rsqrtf((float)(cnt[i] + 1));   // +1 self-loop
}

// ---------------- two-level exclusive scan of cnt -> rowptr ----------------
__global__ __launch_bounds__(256) void k_scan_block(const int* __restrict__ cnt,
                                                    int* __restrict__ rowptr,
                                                    int* __restrict__ partials) {
    __shared__ int s[256];
    int tid = threadIdx.x;
    int i = blockIdx.x * 256 + tid;
    int v = (i < N_NODES) ? cnt[i] : 0;
    s[tid] = v;
    __syncthreads();
#pragma unroll
    for (int off = 1; off < 256; off <<= 1) {
        int t = (tid >= off) ? s[tid - off] : 0;
        __syncthreads();
        s[tid] += t;
        __syncthreads();
    }
    if (i < N_NODES) rowptr[i] = s[tid] - v;      // exclusive within block
    if (tid == 255) partials[blockIdx.x] = s[255];
}

__global__ __launch_bounds__(256) void k_scan_top(int* __restrict__ partials) {
    __shared__ int s[256];
    int tid = threadIdx.x;
    int v = (tid < NBLK) ? partials[tid] : 0;
    s[tid] = v;
    __syncthreads();
#pragma unroll
    for (int off = 1; off < 256; off <<= 1) {
        int t = (tid >= off) ? s[tid - off] : 0;
        __syncthreads();
        s[tid] += t;
        __syncthreads();
    }
    if (tid < NBLK) partials[tid] = s[tid] - v;   // exclusive
}

__global__ void k_scan_add(int* __restrict__ rowptr, const int* __restrict__ partials,
                           int* __restrict__ cursor) {
    int i = blockIdx.x * 256 + threadIdx.x;
    if (i < N_NODES) {
        int r = rowptr[i] + partials[i >> 8];
        rowptr[i] = r;
        cursor[i] = r;
    }
}

// ---------------- scatter edges into CSR buckets: packed (src, norm) ----------------
__global__ void k_scatter(const int* __restrict__ src, const int* __restrict__ dst,
                          const float* __restrict__ dinv,
                          int* __restrict__ cursor, int2* __restrict__ pk) {
    int e = blockIdx.x * 256 + threadIdx.x;
    if (e >= N_EDGES) return;
    int s = src[e];
    int d = dst[e];
    float nrm = dinv[s] * dinv[d];
    int pos = atomicAdd(&cursor[d], 1);
    pk[pos] = make_int2(s, __float_as_int(nrm));
}

// ---------------- fused GEMM: xw[N,128] = x @ [W_mu | W_logstd] ----------------
__global__ __launch_bounds__(256) void k_gemm(const float* __restrict__ x,
                                              const float* __restrict__ Wmu,
                                              const float* __restrict__ Wls,
                                              float* __restrict__ xw) {
    __shared__ float As[64][32];
    __shared__ float Bs[32][CH2];
    const int tid = threadIdx.x;
    const int i0  = blockIdx.x * 64;
    const int tx  = tid & 31;
    const int ty  = tid >> 5;

    float acc[8][4];
#pragma unroll
    for (int r = 0; r < 8; ++r)
#pragma unroll
        for (int j = 0; j < 4; ++j) acc[r][j] = 0.0f;

    for (int k0 = 0; k0 < IN_CH; k0 += 32) {
#pragma unroll
        for (int l = 0; l < 2; ++l) {
            int f   = tid + l * 256;
            int row = f >> 3;
            int c4  = f & 7;
            float4 v = make_float4(0.f, 0.f, 0.f, 0.f);
            if (i0 + row < N_NODES)
                v = *(const float4*)(x + (size_t)(i0 + row) * IN_CH + k0 + c4 * 4);
            *(float4*)&As[row][c4 * 4] = v;
        }
#pragma unroll
        for (int l = 0; l < 4; ++l) {
            int f   = tid + l * 256;
            int row = f >> 5;
            int c   = (f & 31) * 4;
            const float* wp = (c < 64) ? (Wmu + (size_t)(k0 + row) * 64 + c)
                                       : (Wls + (size_t)(k0 + row) * 64 + (c - 64));
            *(float4*)&Bs[row][c] = *(const float4*)wp;
        }
        __syncthreads();

#pragma unroll
        for (int kk = 0; kk < 32; kk += 4) {
            float4 b0 = *(const float4*)&Bs[kk + 0][tx * 4];
            float4 b1 = *(const float4*)&Bs[kk + 1][tx * 4];
            float4 b2 = *(const float4*)&Bs[kk + 2][tx * 4];
            float4 b3 = *(const float4*)&Bs[kk + 3][tx * 4];
#pragma unroll
            for (int r = 0; r < 8; ++r) {
                float4 a = *(const float4*)&As[ty * 8 + r][kk];
                acc[r][0] += a.x * b0.x + a.y * b1.x + a.z * b2.x + a.w * b3.x;
                acc[r][1] += a.x * b0.y + a.y * b1.y + a.z * b2.y + a.w * b3.y;
                acc[r][2] += a.x * b0.z + a.y * b1.z + a.z * b2.z + a.w * b3.z;
                acc[r][3] += a.x * b0.w + a.y * b1.w + a.z * b2.w + a.w * b3.w;
            }
        }
        __syncthreads();
    }

#pragma unroll
    for (int r = 0; r < 8; ++r) {
        int row = i0 + ty * 8 + r;
        if (row < N_NODES) {
            float4 v = make_float4(acc[r][0], acc[r][1], acc[r][2], acc[r][3]);
            *(float4*)(xw + (size_t)row * CH2 + tx * 4) = v;
        }
    }
}

// ---------------- gather: out[i] = sum over edges + self-loop + bias ----------------
// 32 lanes per node, each lane owns 4 channels (float4).
__global__ __launch_bounds__(256) void k_gather(const int* __restrict__ rowptr,
                                                const int* __restrict__ cnt,
                                                const int2* __restrict__ pk,
                                                const float* __restrict__ xw,
                                                const float* __restrict__ dinv,
                                                const float* __restrict__ bmu,
                                                const float* __restrict__ bls,
                                                float* __restrict__ out) {
    int g = blockIdx.x * 256 + threadIdx.x;
    int i = g >> 5, lane = g & 31;
    if (i >= N_NODES) return;

    const float4* xw4 = (const float4*)xw;
    float di = dinv[i];
    // self-loop: xw[i] * dinv[i]^2
    float4 v = xw4[(size_t)i * 32 + lane];
    float s2 = di * di;
    float4 acc = make_float4(v.x * s2, v.y * s2, v.z * s2, v.w * s2);

    int beg = rowptr[i];
    int end = beg + cnt[i];
    for (int e = beg; e < end; ++e) {
        int2 p = pk[e];                       // broadcast across the 32 lanes
        float nrm = __int_as_float(p.y);
        float4 m = xw4[(size_t)p.x * 32 + lane];
        acc.x += m.x * nrm;
        acc.y += m.y * nrm;
        acc.z += m.z * nrm;
        acc.w += m.w * nrm;
    }

    int c0 = lane * 4;
    const float* bb = (c0 < 64) ? (bmu + c0) : (bls + (c0 - 64));
    float4 b = *(const float4*)bb;
    acc.x += b.x; acc.y += b.y; acc.z += b.z; acc.w += b.w;
    float* o = (c0 < 64) ? (out + (size_t)i * 64 + c0)
                         : (out + NODE_OFF + (size_t)i * 64 + (c0 - 64));
    *(float4*)o = acc;
}

extern "C" void kernel_launch(void* const* d_in, const int* in_sizes, int n_in,
                              void* d_out, int out_size, void* d_ws, size_t ws_size,
                              hipStream_t stream) {
    const float* x   = (const float*)d_in[0];
    const int*   ei  = (const int*)d_in[1];
    const float* Wmu = (const float*)d_in[2];
    const float* bmu = (const float*)d_in[3];
    const float* Wls = (const float*)d_in[4];
    const float* bls = (const float*)d_in[5];
    float* out = (float*)d_out;

    const int* src = ei;
    const int* dst = ei + N_EDGES;

    char* ws = (char*)d_ws;
    int*   cnt      = (int*)(ws + 0);              // 200 KB
    float* dinv     = (float*)(ws + 204800);       // 200 KB
    int*   rowptr   = (int*)(ws + 409600);         // 200 KB
    int*   cursor   = (int*)(ws + 614400);         // 200 KB
    int*   partials = (int*)(ws + 819200);         // 1 KB
    int2*  pk       = (int2*)(ws + 1048576);       // 6.4 MB
    float* xw       = (float*)(ws + 8388608);      // 25.6 MB  (total ~34 MB)

    k_zero_cnt<<<NBLK, 256, 0, stream>>>(cnt);
    k_hist<<<(N_EDGES + 255) / 256, 256, 0, stream>>>(dst, cnt);
    k_dinv<<<NBLK, 256, 0, stream>>>(cnt, dinv);
    k_scan_block<<<NBLK, 256, 0, stream>>>(cnt, rowptr, partials);
    k_scan_top<<<1, 256, 0, stream>>>(partials);
    k_scan_add<<<NBLK, 256, 0, stream>>>(rowptr, partials, cursor);
    k_scatter<<<(N_EDGES + 255) / 256, 256, 0, stream>>>(src, dst, dinv, cursor, pk);
    k_gemm<<<(N_NODES + 63) / 64, 256, 0, stream>>>(x, Wmu, Wls, xw);
    k_gather<<<(N_NODES * 32 + 255) / 256, 256, 0, stream>>>(rowptr, cnt, pk, xw, dinv,
                                                             bmu, bls, out);
}

// Round 3
// 280.947 us; speedup vs baseline: 5.7268x; 1.2676x over previous
//
#include <hip/hip_runtime.h>

#define N_NODES 50000
#define IN_CH   256
#define Z_DIM   64
#define N_EDGES 800000
#define CH2     128
#define NODE_OFF (N_NODES * Z_DIM)
#define NBLK    ((N_NODES + 255) / 256)   // 196

typedef __bf16 bf16x8 __attribute__((ext_vector_type(8)));
typedef float  f32x4  __attribute__((ext_vector_type(4)));

__device__ __forceinline__ unsigned short f2bf(float f) {
    unsigned u = __float_as_uint(f);
    return (unsigned short)((u + 0x7FFF + ((u >> 16) & 1)) >> 16);   // RNE
}

// ---------------- histogram (int) ----------------
__global__ void k_zero_cnt(int* __restrict__ cnt) {
    int i = blockIdx.x * 256 + threadIdx.x;
    if (i < N_NODES) cnt[i] = 0;
}

__global__ void k_hist(const int* __restrict__ dst, int* __restrict__ cnt) {
    int e = blockIdx.x * 256 + threadIdx.x;
    if (e < N_EDGES) atomicAdd(&cnt[dst[e]], 1);
}

__global__ void k_dinv(const int* __restrict__ cnt, float* __restrict__ dinv) {
    int i = blockIdx.x * 256 + threadIdx.x;
    if (i < N_NODES) dinv[i] = rsqrtf((float)(cnt[i] + 1));   // +1 self-loop
}

// ---------------- two-level exclusive scan of cnt -> rowptr ----------------
__global__ __launch_bounds__(256) void k_scan_block(const int* __restrict__ cnt,
                                                    int* __restrict__ rowptr,
                                                    int* __restrict__ partials) {
    __shared__ int s[256];
    int tid = threadIdx.x;
    int i = blockIdx.x * 256 + tid;
    int v = (i < N_NODES) ? cnt[i] : 0;
    s[tid] = v;
    __syncthreads();
#pragma unroll
    for (int off = 1; off < 256; off <<= 1) {
        int t = (tid >= off) ? s[tid - off] : 0;
        __syncthreads();
        s[tid] += t;
        __syncthreads();
    }
    if (i < N_NODES) rowptr[i] = s[tid] - v;
    if (tid == 255) partials[blockIdx.x] = s[255];
}

__global__ __launch_bounds__(256) void k_scan_top(int* __restrict__ partials) {
    __shared__ int s[256];
    int tid = threadIdx.x;
    int v = (tid < NBLK) ? partials[tid] : 0;
    s[tid] = v;
    __syncthreads();
#pragma unroll
    for (int off = 1; off < 256; off <<= 1) {
        int t = (tid >= off) ? s[tid - off] : 0;
        __syncthreads();
        s[tid] += t;
        __syncthreads();
    }
    if (tid < NBLK) partials[tid] = s[tid] - v;
}

__global__ void k_scan_add(int* __restrict__ rowptr, const int* __restrict__ partials,
                           int* __restrict__ cursor) {
    int i = blockIdx.x * 256 + threadIdx.x;
    if (i < N_NODES) {
        int r = rowptr[i] + partials[i >> 8];
        rowptr[i] = r;
        cursor[i] = r;
    }
}

// ---------------- scatter edges into CSR buckets: packed (src, norm) ----------------
__global__ void k_scatter(const int* __restrict__ src, const int* __restrict__ dst,
                          const float* __restrict__ dinv,
                          int* __restrict__ cursor, int2* __restrict__ pk) {
    int e = blockIdx.x * 256 + threadIdx.x;
    if (e >= N_EDGES) return;
    int s = src[e];
    int d = dst[e];
    float nrm = dinv[s] * dinv[d];
    int pos = atomicAdd(&cursor[d], 1);
    pk[pos] = make_int2(s, __float_as_int(nrm));
}

// ---------------- weight transpose + bf16 convert: WbT[n][k], n in [0,128) ----------------
__global__ void k_convw(const float* __restrict__ Wmu, const float* __restrict__ Wls,
                        unsigned short* __restrict__ WbT) {
    int g = blockIdx.x * 256 + threadIdx.x;   // 32768
    int n = g >> 8, k = g & 255;
    float v = (n < 64) ? Wmu[(size_t)k * 64 + n] : Wls[(size_t)k * 64 + (n - 64)];
    WbT[(size_t)n * 256 + k] = f2bf(v);
}

// ---------------- MFMA GEMM: xw[N,128] = bf16(x) @ bf16([W_mu|W_ls]), fp32 acc ----------------
// Block = 256 thr (4 waves), 32 rows. Wave w: rows (w&1)*16, cols (w>>1)*64 (4 n-tiles).
#define LDP 264   // padded LDS row stride in ushorts (+8 -> 2-way-only bank aliasing)
__global__ __launch_bounds__(256) void k_gemm(const float* __restrict__ x,
                                              const unsigned short* __restrict__ WbT,
                                              float* __restrict__ xw) {
    __shared__ unsigned short As[32 * LDP];
    const int tid = threadIdx.x;
    const int r0  = blockIdx.x * 32;

    // ---- stage 32 rows x 256 cols of x into LDS as bf16 ----
    {
        int row_l = tid >> 3;            // 0..31
        int cb    = (tid & 7) * 32;      // 0,32,...,224
        int row   = r0 + row_l;
        unsigned short* dp = As + row_l * LDP + cb;
        if (row < N_NODES) {
            const float4* xp = (const float4*)(x + (size_t)row * IN_CH + cb);
#pragma unroll
            for (int i = 0; i < 4; ++i) {
                float4 a = xp[2 * i];
                float4 b = xp[2 * i + 1];
                uint4 w;
                w.x = (unsigned)f2bf(a.x) | ((unsigned)f2bf(a.y) << 16);
                w.y = (unsigned)f2bf(a.z) | ((unsigned)f2bf(a.w) << 16);
                w.z = (unsigned)f2bf(b.x) | ((unsigned)f2bf(b.y) << 16);
                w.w = (unsigned)f2bf(b.z) | ((unsigned)f2bf(b.w) << 16);
                *(uint4*)(dp + i * 8) = w;
            }
        } else {
            uint4 z = make_uint4(0, 0, 0, 0);
#pragma unroll
            for (int i = 0; i < 4; ++i) *(uint4*)(dp + i * 8) = z;
        }
    }
    __syncthreads();

    const int wv   = tid >> 6;
    const int lane = tid & 63;
    const int m    = lane & 15;          // A row / B col / D col
    const int q    = lane >> 4;          // quad
    const int row_half = (wv & 1) * 16;
    const int col_half = (wv >> 1) * 64;

    f32x4 acc[4] = {};
    const unsigned short* ap = As + (row_half + m) * LDP + q * 8;
    const unsigned short* bp = WbT + (size_t)(col_half + m) * 256 + q * 8;

#pragma unroll
    for (int k0 = 0; k0 < IN_CH; k0 += 32) {
        bf16x8 af = *(const bf16x8*)(ap + k0);
#pragma unroll
        for (int nt = 0; nt < 4; ++nt) {
            bf16x8 bf_ = *(const bf16x8*)(bp + (size_t)nt * 16 * 256 + k0);
            acc[nt] = __builtin_amdgcn_mfma_f32_16x16x32_bf16(af, bf_, acc[nt], 0, 0, 0);
        }
    }

    // ---- epilogue: D layout col=lane&15, row=quad*4+reg ----
#pragma unroll
    for (int nt = 0; nt < 4; ++nt) {
#pragma unroll
        for (int r = 0; r < 4; ++r) {
            int row = r0 + row_half + q * 4 + r;
            if (row < N_NODES)
                xw[(size_t)row * CH2 + col_half + nt * 16 + m] = acc[nt][r];
        }
    }
}

// ---------------- gather: out[i] = self-loop + sum_e xw[src_e]*nrm_e + bias ----------------
__global__ __launch_bounds__(256) void k_gather(const int* __restrict__ rowptr,
                                                const int* __restrict__ cnt,
                                                const int2* __restrict__ pk,
                                                const float* __restrict__ xw,
                                                const float* __restrict__ dinv,
                                                const float* __restrict__ bmu,
                                                const float* __restrict__ bls,
                                                float* __restrict__ out) {
    int g = blockIdx.x * 256 + threadIdx.x;
    int i = g >> 5, lane = g & 31;
    if (i >= N_NODES) return;

    const float4* xw4 = (const float4*)xw;
    float di = dinv[i];
    float4 v = xw4[(size_t)i * 32 + lane];
    float s2 = di * di;
    float4 acc = make_float4(v.x * s2, v.y * s2, v.z * s2, v.w * s2);

    int beg = rowptr[i];
    int end = beg + cnt[i];
    for (int e = beg; e < end; ++e) {
        int2 p = pk[e];
        float nrm = __int_as_float(p.y);
        float4 mv = xw4[(size_t)p.x * 32 + lane];
        acc.x += mv.x * nrm;
        acc.y += mv.y * nrm;
        acc.z += mv.z * nrm;
        acc.w += mv.w * nrm;
    }

    int c0 = lane * 4;
    const float* bb = (c0 < 64) ? (bmu + c0) : (bls + (c0 - 64));
    float4 b = *(const float4*)bb;
    acc.x += b.x; acc.y += b.y; acc.z += b.z; acc.w += b.w;
    float* o = (c0 < 64) ? (out + (size_t)i * 64 + c0)
                         : (out + NODE_OFF + (size_t)i * 64 + (c0 - 64));
    *(float4*)o = acc;
}

extern "C" void kernel_launch(void* const* d_in, const int* in_sizes, int n_in,
                              void* d_out, int out_size, void* d_ws, size_t ws_size,
                              hipStream_t stream) {
    const float* x   = (const float*)d_in[0];
    const int*   ei  = (const int*)d_in[1];
    const float* Wmu = (const float*)d_in[2];
    const float* bmu = (const float*)d_in[3];
    const float* Wls = (const float*)d_in[4];
    const float* bls = (const float*)d_in[5];
    float* out = (float*)d_out;

    const int* src = ei;
    const int* dst = ei + N_EDGES;

    char* ws = (char*)d_ws;
    int*            cnt      = (int*)(ws + 0);         // 200 KB
    float*          dinv     = (float*)(ws + 204800);  // 200 KB
    int*            rowptr   = (int*)(ws + 409600);    // 200 KB
    int*            cursor   = (int*)(ws + 614400);    // 200 KB
    int*            partials = (int*)(ws + 819200);    // ~1 KB
    unsigned short* WbT      = (unsigned short*)(ws + 827392);  // 64 KB
    int2*           pk       = (int2*)(ws + 1048576);  // 6.4 MB
    float*          xw       = (float*)(ws + 8388608); // 25.6 MB

    k_zero_cnt<<<NBLK, 256, 0, stream>>>(cnt);
    k_hist<<<(N_EDGES + 255) / 256, 256, 0, stream>>>(dst, cnt);
    k_dinv<<<NBLK, 256, 0, stream>>>(cnt, dinv);
    k_scan_block<<<NBLK, 256, 0, stream>>>(cnt, rowptr, partials);
    k_scan_top<<<1, 256, 0, stream>>>(partials);
    k_scan_add<<<NBLK, 256, 0, stream>>>(rowptr, partials, cursor);
    k_scatter<<<(N_EDGES + 255) / 256, 256, 0, stream>>>(src, dst, dinv, cursor, pk);
    k_convw<<<128, 256, 0, stream>>>(Wmu, Wls, WbT);
    k_gemm<<<(N_NODES + 31) / 32, 256, 0, stream>>>(x, WbT, xw);
    k_gather<<<(N_NODES * 32 + 255) / 256, 256, 0, stream>>>(rowptr, cnt, pk, xw, dinv,
                                                             bmu, bls, out);
}

// Round 4
// 254.465 us; speedup vs baseline: 6.3228x; 1.1041x over previous
//
#include <hip/hip_runtime.h>

#define N_NODES 50000
#define IN_CH   256
#define Z_DIM   64
#define N_EDGES 800000
#define CH2     128
#define NODE_OFF (N_NODES * Z_DIM)
#define NBLK    ((N_NODES + 255) / 256)   // 196
#define NW      32768                     // 128*256 weight elements

typedef __bf16 bf16x8 __attribute__((ext_vector_type(8)));
typedef float  f32x4  __attribute__((ext_vector_type(4)));

__device__ __forceinline__ unsigned short f2bf(float f) {
    unsigned u = __float_as_uint(f);
    return (unsigned short)((u + 0x7FFF + ((u >> 16) & 1)) >> 16);   // RNE
}
__device__ __forceinline__ float bf_lo(unsigned w) { return __uint_as_float(w << 16); }
__device__ __forceinline__ float bf_hi(unsigned w) { return __uint_as_float(w & 0xFFFF0000u); }

// ---------------- fused: zero cnt + weight transpose/convert ----------------
__global__ void k_pre0(int* __restrict__ cnt,
                       const float* __restrict__ Wmu, const float* __restrict__ Wls,
                       unsigned short* __restrict__ WbT) {
    int g = blockIdx.x * 256 + threadIdx.x;
    if (g < N_NODES) cnt[g] = 0;
    int h = g - N_NODES;
    if (h >= 0 && h < NW) {
        int n = h >> 8, k = h & 255;
        float v = (n < 64) ? Wmu[(size_t)k * 64 + n] : Wls[(size_t)k * 64 + (n - 64)];
        WbT[(size_t)n * 256 + k] = f2bf(v);
    }
}

__global__ void k_hist(const int* __restrict__ dst, int* __restrict__ cnt) {
    int e = blockIdx.x * 256 + threadIdx.x;
    if (e < N_EDGES) atomicAdd(&cnt[dst[e]], 1);
}

// ---------------- scan block (+dinv) ----------------
__global__ __launch_bounds__(256) void k_scan_block(const int* __restrict__ cnt,
                                                    int* __restrict__ rowptr,
                                                    int* __restrict__ partials,
                                                    float* __restrict__ dinv) {
    __shared__ int s[256];
    int tid = threadIdx.x;
    int i = blockIdx.x * 256 + tid;
    int v = (i < N_NODES) ? cnt[i] : 0;
    if (i < N_NODES) dinv[i] = rsqrtf((float)(v + 1));   // +1 self-loop
    s[tid] = v;
    __syncthreads();
#pragma unroll
    for (int off = 1; off < 256; off <<= 1) {
        int t = (tid >= off) ? s[tid - off] : 0;
        __syncthreads();
        s[tid] += t;
        __syncthreads();
    }
    if (i < N_NODES) rowptr[i] = s[tid] - v;
    if (tid == 255) partials[blockIdx.x] = s[255];
}

__global__ __launch_bounds__(256) void k_scan_top(int* __restrict__ partials) {
    __shared__ int s[256];
    int tid = threadIdx.x;
    int v = (tid < NBLK) ? partials[tid] : 0;
    s[tid] = v;
    __syncthreads();
#pragma unroll
    for (int off = 1; off < 256; off <<= 1) {
        int t = (tid >= off) ? s[tid - off] : 0;
        __syncthreads();
        s[tid] += t;
        __syncthreads();
    }
    if (tid < NBLK) partials[tid] = s[tid] - v;
}

__global__ void k_scan_add(int* __restrict__ rowptr, const int* __restrict__ partials,
                           int* __restrict__ cursor) {
    int i = blockIdx.x * 256 + threadIdx.x;
    if (i < N_NODES) {
        int r = rowptr[i] + partials[i >> 8];
        rowptr[i] = r;
        cursor[i] = r;
    }
}

// ---------------- scatter edges into CSR buckets: packed (src, norm) ----------------
__global__ void k_scatter(const int* __restrict__ src, const int* __restrict__ dst,
                          const float* __restrict__ dinv,
                          int* __restrict__ cursor, int2* __restrict__ pk) {
    int e = blockIdx.x * 256 + threadIdx.x;
    if (e >= N_EDGES) return;
    int s = src[e];
    int d = dst[e];
    float nrm = dinv[s] * dinv[d];
    int pos = atomicAdd(&cursor[d], 1);
    pk[pos] = make_int2(s, __float_as_int(nrm));
}

// ---------------- MFMA GEMM: xwb[N,128](bf16) = bf16(x) @ WbT^T, fp32 acc ----------------
#define LDP 264   // A-tile LDS row stride (ushorts)
#define CSP 132   // C staging stride (floats); 32*132*4 = 16896 = 32*264*2
__global__ __launch_bounds__(256) void k_gemm(const float* __restrict__ x,
                                              const unsigned short* __restrict__ WbT,
                                              unsigned short* __restrict__ xwb) {
    __shared__ __align__(16) char smem[32 * LDP * 2];
    unsigned short* As = (unsigned short*)smem;
    float*          Cs = (float*)smem;
    const int tid = threadIdx.x;
    const int r0  = blockIdx.x * 32;

    // ---- stage 32 rows x 256 cols of x into LDS as bf16 ----
    {
        int row_l = tid >> 3;
        int cb    = (tid & 7) * 32;
        int row   = r0 + row_l;
        unsigned short* dp = As + row_l * LDP + cb;
        if (row < N_NODES) {
            const float4* xp = (const float4*)(x + (size_t)row * IN_CH + cb);
#pragma unroll
            for (int i = 0; i < 4; ++i) {
                float4 a = xp[2 * i];
                float4 b = xp[2 * i + 1];
                uint4 w;
                w.x = (unsigned)f2bf(a.x) | ((unsigned)f2bf(a.y) << 16);
                w.y = (unsigned)f2bf(a.z) | ((unsigned)f2bf(a.w) << 16);
                w.z = (unsigned)f2bf(b.x) | ((unsigned)f2bf(b.y) << 16);
                w.w = (unsigned)f2bf(b.z) | ((unsigned)f2bf(b.w) << 16);
                *(uint4*)(dp + i * 8) = w;
            }
        } else {
            uint4 z = make_uint4(0, 0, 0, 0);
#pragma unroll
            for (int i = 0; i < 4; ++i) *(uint4*)(dp + i * 8) = z;
        }
    }
    __syncthreads();

    const int wv   = tid >> 6;
    const int lane = tid & 63;
    const int m    = lane & 15;
    const int q    = lane >> 4;
    const int row_half = (wv & 1) * 16;
    const int col_half = (wv >> 1) * 64;

    f32x4 acc[4] = {};
    const unsigned short* ap = As + (row_half + m) * LDP + q * 8;
    const unsigned short* bp = WbT + (size_t)(col_half + m) * 256 + q * 8;

#pragma unroll
    for (int k0 = 0; k0 < IN_CH; k0 += 32) {
        bf16x8 af = *(const bf16x8*)(ap + k0);
#pragma unroll
        for (int nt = 0; nt < 4; ++nt) {
            bf16x8 bf_ = *(const bf16x8*)(bp + (size_t)nt * 16 * 256 + k0);
            acc[nt] = __builtin_amdgcn_mfma_f32_16x16x32_bf16(af, bf_, acc[nt], 0, 0, 0);
        }
    }

    // ---- epilogue: stage to LDS (D layout col=m, row=q*4+r), then coalesced bf16 store ----
    __syncthreads();   // done reading As
#pragma unroll
    for (int nt = 0; nt < 4; ++nt)
#pragma unroll
        for (int r = 0; r < 4; ++r)
            Cs[(row_half + q * 4 + r) * CSP + col_half + nt * 16 + m] = acc[nt][r];
    __syncthreads();

    {
        int row_l = tid >> 3;             // 0..31
        int c0    = (tid & 7) * 16;       // 0,16,...,112
        int row   = r0 + row_l;
        if (row < N_NODES) {
            const float* cp = Cs + row_l * CSP + c0;
            uint4 w;
            float4 a = *(const float4*)(cp + 0);
            float4 b = *(const float4*)(cp + 4);
            float4 c = *(const float4*)(cp + 8);
            float4 d = *(const float4*)(cp + 12);
            uint4 w0, w1;
            w0.x = (unsigned)f2bf(a.x) | ((unsigned)f2bf(a.y) << 16);
            w0.y = (unsigned)f2bf(a.z) | ((unsigned)f2bf(a.w) << 16);
            w0.z = (unsigned)f2bf(b.x) | ((unsigned)f2bf(b.y) << 16);
            w0.w = (unsigned)f2bf(b.z) | ((unsigned)f2bf(b.w) << 16);
            w1.x = (unsigned)f2bf(c.x) | ((unsigned)f2bf(c.y) << 16);
            w1.y = (unsigned)f2bf(c.z) | ((unsigned)f2bf(c.w) << 16);
            w1.z = (unsigned)f2bf(d.x) | ((unsigned)f2bf(d.y) << 16);
            w1.w = (unsigned)f2bf(d.z) | ((unsigned)f2bf(d.w) << 16);
            uint4* op = (uint4*)(xwb + (size_t)row * CH2 + c0);
            op[0] = w0;
            op[1] = w1;
            (void)w;
        }
    }
}

// ---------------- gather: 16 lanes/node, bf16 rows, fp32 accumulate ----------------
__global__ __launch_bounds__(256) void k_gather(const int* __restrict__ rowptr,
                                                const int* __restrict__ cnt,
                                                const int2* __restrict__ pk,
                                                const unsigned short* __restrict__ xwb,
                                                const float* __restrict__ dinv,
                                                const float* __restrict__ bmu,
                                                const float* __restrict__ bls,
                                                float* __restrict__ out) {
    int g = blockIdx.x * 256 + threadIdx.x;
    int i = g >> 4, lane = g & 15;
    if (i >= N_NODES) return;

    float di = dinv[i];
    float s2 = di * di;
    float acc[8];
    {
        uint4 w = *(const uint4*)(xwb + (size_t)i * CH2 + lane * 8);
        acc[0] = bf_lo(w.x) * s2; acc[1] = bf_hi(w.x) * s2;
        acc[2] = bf_lo(w.y) * s2; acc[3] = bf_hi(w.y) * s2;
        acc[4] = bf_lo(w.z) * s2; acc[5] = bf_hi(w.z) * s2;
        acc[6] = bf_lo(w.w) * s2; acc[7] = bf_hi(w.w) * s2;
    }

    int beg = rowptr[i];
    int end = beg + cnt[i];
    for (int e = beg; e < end; ++e) {
        int2 p = pk[e];
        float nrm = __int_as_float(p.y);
        uint4 w = *(const uint4*)(xwb + (size_t)p.x * CH2 + lane * 8);
        acc[0] += bf_lo(w.x) * nrm; acc[1] += bf_hi(w.x) * nrm;
        acc[2] += bf_lo(w.y) * nrm; acc[3] += bf_hi(w.y) * nrm;
        acc[4] += bf_lo(w.z) * nrm; acc[5] += bf_hi(w.z) * nrm;
        acc[6] += bf_lo(w.w) * nrm; acc[7] += bf_hi(w.w) * nrm;
    }

    int c0 = lane * 8;
    const float* bb = (c0 < 64) ? (bmu + c0) : (bls + (c0 - 64));
    float4 b0 = *(const float4*)(bb + 0);
    float4 b1 = *(const float4*)(bb + 4);
    float* o = (c0 < 64) ? (out + (size_t)i * 64 + c0)
                         : (out + NODE_OFF + (size_t)i * 64 + (c0 - 64));
    float4 r0 = make_float4(acc[0] + b0.x, acc[1] + b0.y, acc[2] + b0.z, acc[3] + b0.w);
    float4 r1 = make_float4(acc[4] + b1.x, acc[5] + b1.y, acc[6] + b1.z, acc[7] + b1.w);
    *(float4*)(o + 0) = r0;
    *(float4*)(o + 4) = r1;
}

extern "C" void kernel_launch(void* const* d_in, const int* in_sizes, int n_in,
                              void* d_out, int out_size, void* d_ws, size_t ws_size,
                              hipStream_t stream) {
    const float* x   = (const float*)d_in[0];
    const int*   ei  = (const int*)d_in[1];
    const float* Wmu = (const float*)d_in[2];
    const float* bmu = (const float*)d_in[3];
    const float* Wls = (const float*)d_in[4];
    const float* bls = (const float*)d_in[5];
    float* out = (float*)d_out;

    const int* src = ei;
    const int* dst = ei + N_EDGES;

    char* ws = (char*)d_ws;
    int*            cnt      = (int*)(ws + 0);                  // 200 KB
    float*          dinv     = (float*)(ws + 204800);           // 200 KB
    int*            rowptr   = (int*)(ws + 409600);             // 200 KB
    int*            cursor   = (int*)(ws + 614400);             // 200 KB
    int*            partials = (int*)(ws + 819200);             // ~1 KB
    unsigned short* WbT      = (unsigned short*)(ws + 827392);  // 64 KB
    int2*           pk       = (int2*)(ws + 1048576);           // 6.4 MB
    unsigned short* xwb      = (unsigned short*)(ws + 8388608); // 12.8 MB

    k_pre0<<<(N_NODES + NW + 255) / 256, 256, 0, stream>>>(cnt, Wmu, Wls, WbT);
    k_hist<<<(N_EDGES + 255) / 256, 256, 0, stream>>>(dst, cnt);
    k_scan_block<<<NBLK, 256, 0, stream>>>(cnt, rowptr, partials, dinv);
    k_scan_top<<<1, 256, 0, stream>>>(partials);
    k_scan_add<<<NBLK, 256, 0, stream>>>(rowptr, partials, cursor);
    k_scatter<<<(N_EDGES + 255) / 256, 256, 0, stream>>>(src, dst, dinv, cursor, pk);
    k_gemm<<<(N_NODES + 31) / 32, 256, 0, stream>>>(x, WbT, xwb);
    k_gather<<<(N_NODES * 16 + 255) / 256, 256, 0, stream>>>(rowptr, cnt, pk, xwb, dinv,
                                                             bmu, bls, out);
}